// Round 1
// baseline (84.201 us; speedup 1.0000x reference)
//
#include <hip/hip_runtime.h>
#include <math.h>

// Problem dims (fixed by the reference)
#define BB 8
#define NN 1024
#define FF 128
#define EE 64
#define LOG2F_ 0.6931471805599453f

// ---------------------------------------------------------------------------
// Kernel A: per-row MLP.  kv = softplus(h@W1+b1)-log2 @ W2 + b2, masked.
// One wave per row (lane = e in [0,64)). 256 blocks x 32 rows each.
// ---------------------------------------------------------------------------
__global__ __launch_bounds__(256) void mlp_kernel(
    const float* __restrict__ h,  const float* __restrict__ W1,
    const float* __restrict__ b1, const float* __restrict__ W2,
    const float* __restrict__ b2, const float* __restrict__ mask,
    float* __restrict__ kout, float* __restrict__ vout)
{
    __shared__ float W1s[FF * EE];   // 32 KB, [f][e]
    __shared__ float hbuf[4][FF];    // per-wave h row
    __shared__ float hid[4][EE];     // per-wave hidden activations

    const int t = threadIdx.x;
    const int wave = t >> 6;
    const int lane = t & 63;

    // stage W1 (32 KB) cooperatively, float4
    for (int idx = t * 4; idx < FF * EE; idx += 256 * 4) {
        *(float4*)&W1s[idx] = *(const float4*)&W1[idx];
    }
    __syncthreads();

    const float b1e = b1[lane];
    const float b2k = b2[lane];
    const float b2v = b2[EE + lane];

    const int row0 = blockIdx.x * 32 + wave * 8;
    for (int rr = 0; rr < 8; ++rr) {
        const int row = row0 + rr;
        // stage h row (128 f32) into this wave's buffer
        hbuf[wave][lane]      = h[row * FF + lane];
        hbuf[wave][64 + lane] = h[row * FF + 64 + lane];
        __syncthreads();

        float pre = b1e;
        #pragma unroll 8
        for (int f = 0; f < FF; ++f)
            pre += hbuf[wave][f] * W1s[f * EE + lane];

        // numerically-stable softplus, then shift by log(2)
        float sp = (pre > 0.f) ? (pre + log1pf(expf(-pre)))
                               : log1pf(expf(pre));
        hid[wave][lane] = sp - LOG2F_;
        __syncthreads();

        float kacc = b2k, vacc = b2v;
        #pragma unroll 8
        for (int d = 0; d < EE; ++d) {
            const float hd = hid[wave][d];
            kacc += hd * W2[d * 129 + lane];        // col e
            vacc += hd * W2[d * 129 + 64 + lane];   // col 64+e
        }
        const float m = mask[row];
        kout[row * EE + lane] = kacc * m;
        vout[row * EE + lane] = vacc * m;
        __syncthreads();   // hbuf/hid reused next iteration
    }
}

// ---------------------------------------------------------------------------
// Kernel B: fused pairwise stage.
// Grid = B * N/4 blocks, 256 threads = 4 waves, one wave per output row i.
// k_i lives in 64 VGPRs per lane; v_j tiles staged in LDS; lane owns one j
// per 64-wide tile; 64-lane shuffle reduce at the end.
// ---------------------------------------------------------------------------
__global__ __launch_bounds__(256) void pair_kernel(
    const float* __restrict__ kmu, const float* __restrict__ vmu,
    const float* __restrict__ pos, const float* __restrict__ mask,
    float* __restrict__ out)
{
    __shared__ float vt[64][68];   // v tile, padded stride 68 (bank shift 4)
    __shared__ float pt[64][4];    // positions tile
    __shared__ float msum_s[4];

    const int t = threadIdx.x;
    const int wave = t >> 6;
    const int lane = t & 63;
    const int b = blockIdx.x >> 8;             // 256 i-tiles per batch
    const int i = (blockIdx.x & 255) * 4 + wave;
    const int rowI = b * NN + i;

    // block-wide mask sum for batch b (ref: atoms_mask.sum(-1))
    float ps = mask[b * NN + t] + mask[b * NN + 256 + t]
             + mask[b * NN + 512 + t] + mask[b * NN + 768 + t];
    #pragma unroll
    for (int off = 32; off; off >>= 1) ps += __shfl_xor(ps, off, 64);
    if (lane == 0) msum_s[wave] = ps;
    __syncthreads();
    const float msum = msum_s[0] + msum_s[1] + msum_s[2] + msum_s[3];

    // k_i into registers (same values in all lanes; broadcast loads)
    float4 kr[16];
    #pragma unroll
    for (int q = 0; q < 16; ++q)
        kr[q] = *(const float4*)&kmu[rowI * EE + q * 4];

    const float pix = pos[rowI * 3 + 0];
    const float piy = pos[rowI * 3 + 1];
    const float piz = pos[rowI * 3 + 2];

    float ax = 0.f, ay = 0.f, az = 0.f;

    for (int jt = 0; jt < NN / 64; ++jt) {
        // stage v tile: 64 j-rows x 64 e  (1024 float4s, 4 per thread)
        #pragma unroll
        for (int q = 0; q < 4; ++q) {
            const int fidx = t + q * 256;        // 0..1023
            const int jj = fidx >> 4;            // j within tile
            const int e4 = fidx & 15;            // float4 index within row
            *(float4*)&vt[jj][e4 * 4] =
                *(const float4*)&vmu[(b * NN + jt * 64 + jj) * EE + e4 * 4];
        }
        if (t < 64) {
            const int jr = b * NN + jt * 64 + t;
            pt[t][0] = pos[jr * 3 + 0];
            pt[t][1] = pos[jr * 3 + 1];
            pt[t][2] = pos[jr * 3 + 2];
        }
        __syncthreads();

        // this lane's j for this tile
        float s = 0.f;
        #pragma unroll
        for (int q = 0; q < 16; ++q) {
            const float4 v4 = *(const float4*)&vt[lane][q * 4];
            s += kr[q].x * v4.x + kr[q].y * v4.y
               + kr[q].z * v4.z + kr[q].w * v4.w;
        }
        s *= 0.125f;   // 1/sqrt(E)

        const float dx = pix - pt[lane][0];
        const float dy = piy - pt[lane][1];
        const float dz = piz - pt[lane][2];
        const float r  = sqrtf(dx * dx + dy * dy + dz * dz);
        const float w  = s / (r + 1e-8f);   // diagonal: dx=dy=dz=0 -> 0 contribution
        ax += dx * w;
        ay += dy * w;
        az += dz * w;
        __syncthreads();   // before next tile overwrites vt
    }

    // wave reduction over the 64 j-slots
    #pragma unroll
    for (int off = 32; off; off >>= 1) {
        ax += __shfl_xor(ax, off, 64);
        ay += __shfl_xor(ay, off, 64);
        az += __shfl_xor(az, off, 64);
    }

    if (lane == 0) {
        const float mi  = mask[rowI];
        const float inv = 1.f / msum;
        out[rowI * 3 + 0] = tanhf(ax * inv) * mi;
        out[rowI * 3 + 1] = tanhf(ay * inv) * mi;
        out[rowI * 3 + 2] = tanhf(az * inv) * mi;
    }
}

// ---------------------------------------------------------------------------
extern "C" void kernel_launch(void* const* d_in, const int* in_sizes, int n_in,
                              void* d_out, int out_size, void* d_ws, size_t ws_size,
                              hipStream_t stream) {
    const float* pos  = (const float*)d_in[0];   // (8,1024,3)
    const float* mask = (const float*)d_in[1];   // (8,1024)
    const float* h    = (const float*)d_in[2];   // (8,1024,128)
    const float* W1   = (const float*)d_in[3];   // (128,64)
    const float* b1   = (const float*)d_in[4];   // (64,)
    const float* W2   = (const float*)d_in[5];   // (64,129)
    const float* b2   = (const float*)d_in[6];   // (129,)
    float* out = (float*)d_out;                  // (8,1024,3)

    float* kbuf = (float*)d_ws;                  // 8*1024*64 f32 = 2 MB
    float* vbuf = kbuf + BB * NN * EE;           // next 2 MB

    mlp_kernel<<<256, 256, 0, stream>>>(h, W1, b1, W2, b2, mask, kbuf, vbuf);
    pair_kernel<<<BB * NN / 4, 256, 0, stream>>>(kbuf, vbuf, pos, mask, out);
}

// Round 2
// 38.388 us; speedup vs baseline: 2.1934x; 2.1934x over previous
//
#include <hip/hip_runtime.h>
#include <hip/hip_bf16.h>
#include <math.h>

// Problem dims (fixed by the reference)
#define BB 8
#define NN 1024
#define FF 128
#define EE 64
#define JC 8              // j-chunks (parallelism + partial buffers)
#define LOG2F_ 0.69314718055994531f

typedef __attribute__((ext_vector_type(4))) float f32x4;
typedef __attribute__((ext_vector_type(8))) short bf16x8;

__device__ __forceinline__ float softplus_shift(float x) {
    // softplus(x) - log(2), numerically stable
    return fmaxf(x, 0.f) + log1pf(expf(-fabsf(x))) - LOG2F_;
}

// ---------------------------------------------------------------------------
// Kernel A: per-row MLP -> k (bf16, pre-scaled by 1/sqrt(E)=0.125) and v (bf16)
// 512 blocks x 256 threads; each wave computes 4 rows (lane = e).
// ---------------------------------------------------------------------------
__global__ __launch_bounds__(256) void mlp_kernel(
    const float* __restrict__ h,  const float* __restrict__ W1,
    const float* __restrict__ b1, const float* __restrict__ W2,
    const float* __restrict__ b2, const float* __restrict__ mask,
    __hip_bfloat16* __restrict__ kbf, __hip_bfloat16* __restrict__ vbf)
{
    __shared__ float W1s[FF * EE];     // 32 KB, [f][e]
    __shared__ float hb[4][4 * FF];    // per-wave: 4 h rows, flat (8 KB)
    __shared__ float hid[4][4][EE];    // per-wave: 4 hidden rows (4 KB)

    const int t = threadIdx.x;
    const int wave = t >> 6;
    const int lane = t & 63;

    // stage W1 (32 KB) cooperatively
    for (int idx = t * 4; idx < FF * EE; idx += 256 * 4)
        *(float4*)&W1s[idx] = *(const float4*)&W1[idx];

    const int row0 = blockIdx.x * 16 + wave * 4;

    // stage this wave's 4 h rows (contiguous 512 floats)
    {
        const float4* src = (const float4*)&h[row0 * FF];
        float4* dst = (float4*)&hb[wave][0];
        dst[lane]      = src[lane];
        dst[64 + lane] = src[64 + lane];
    }
    __syncthreads();

    // stage 1: pre = h @ W1 + b1   (4 rows at once, lane = output col e)
    const float b1e = b1[lane];
    float a0 = b1e, a1 = b1e, a2 = b1e, a3 = b1e;
    #pragma unroll 4
    for (int f = 0; f < FF; ++f) {
        const float w = W1s[f * EE + lane];
        a0 += hb[wave][f] * w;
        a1 += hb[wave][FF + f] * w;
        a2 += hb[wave][2 * FF + f] * w;
        a3 += hb[wave][3 * FF + f] * w;
    }
    hid[wave][0][lane] = softplus_shift(a0);
    hid[wave][1][lane] = softplus_shift(a1);
    hid[wave][2][lane] = softplus_shift(a2);
    hid[wave][3][lane] = softplus_shift(a3);
    __syncthreads();

    // stage 2: kv = hid @ W2 + b2   (cols: [0,64)=k, [64,128)=v; col 128 unused)
    float kacc[4], vacc[4];
    const float b2k = b2[lane], b2v = b2[EE + lane];
    #pragma unroll
    for (int r = 0; r < 4; ++r) { kacc[r] = b2k; vacc[r] = b2v; }
    #pragma unroll 4
    for (int d = 0; d < EE; ++d) {
        const float w2k = W2[d * 129 + lane];
        const float w2v = W2[d * 129 + EE + lane];
        #pragma unroll
        for (int r = 0; r < 4; ++r) {
            const float hv = hid[wave][r][d];
            kacc[r] += hv * w2k;
            vacc[r] += hv * w2v;
        }
    }
    #pragma unroll
    for (int r = 0; r < 4; ++r) {
        const float m = mask[row0 + r];
        kbf[(row0 + r) * EE + lane] = __float2bfloat16(kacc[r] * 0.125f * m);
        vbf[(row0 + r) * EE + lane] = __float2bfloat16(vacc[r] * m);
    }
}

// ---------------------------------------------------------------------------
// Kernel B: pairwise stage via MFMA.
// Grid = BB * 16 * JC blocks x 256 threads (4 waves).
// Each wave owns a 16-row i-strip (A-frags = k rows, in registers for the
// whole kernel) and sweeps its block's 128-wide j-chunk in 16-j tiles:
//   S-tile(16x16) = 2x mfma_f32_16x16x32_bf16, B-frags (v rows) straight
//   from L2-resident global. Epilogue: w = s * rsqrt(r2), accumulate dir*w.
// Partials (per j-chunk) written to ws; no atomics.
// ---------------------------------------------------------------------------
__global__ __launch_bounds__(256) void pair_kernel(
    const __hip_bfloat16* __restrict__ kbf,
    const __hip_bfloat16* __restrict__ vbf,
    const float* __restrict__ pos,
    float* __restrict__ partial)
{
    __shared__ float posS[(NN / JC) * 3];   // this block's j-chunk positions

    const int t = threadIdx.x;
    const int wave = t >> 6;
    const int lane = t & 63;

    const int bx = blockIdx.x;
    const int b  = bx / (16 * JC);
    const int rem = bx % (16 * JC);
    const int ib = rem / JC;         // i-block of 64 rows
    const int jc = rem % JC;         // j-chunk of 128 cols
    const int i0w = ib * 64 + wave * 16;   // wave's 16-row i-strip
    const int jbase = jc * (NN / JC);

    // stage j-chunk positions (128 rows x 3 f32 = 384 floats), coalesced
    for (int idx = t; idx < (NN / JC) * 3; idx += 256)
        posS[idx] = pos[(b * NN + jbase) * 3 + idx];
    __syncthreads();

    const int lrow = lane & 15;      // A row / B col within 16
    const int kgrp = lane >> 4;      // k-block selector

    // A-fragments: this wave's k rows, loaded once (stay in VGPRs)
    const bf16x8 afrag0 = *(const bf16x8*)&kbf[(b * NN + i0w + lrow) * EE + kgrp * 8];
    const bf16x8 afrag1 = *(const bf16x8*)&kbf[(b * NN + i0w + lrow) * EE + 32 + kgrp * 8];

    // i-positions for this lane's 4 accumulator rows: row = kgrp*4 + r
    float pix[4], piy[4], piz[4];
    #pragma unroll
    for (int r = 0; r < 4; ++r) {
        const int ir = (b * NN + i0w + kgrp * 4 + r) * 3;
        pix[r] = pos[ir + 0];
        piy[r] = pos[ir + 1];
        piz[r] = pos[ir + 2];
    }

    float ax[4] = {0.f, 0.f, 0.f, 0.f};
    float ay[4] = {0.f, 0.f, 0.f, 0.f};
    float az[4] = {0.f, 0.f, 0.f, 0.f};

    for (int jt = 0; jt < (NN / JC) / 16; ++jt) {
        const int jrow = (b * NN + jbase + jt * 16 + lrow) * EE;
        const bf16x8 bfrag0 = *(const bf16x8*)&vbf[jrow + kgrp * 8];
        const bf16x8 bfrag1 = *(const bf16x8*)&vbf[jrow + 32 + kgrp * 8];

        f32x4 acc = {0.f, 0.f, 0.f, 0.f};
        acc = __builtin_amdgcn_mfma_f32_16x16x32_bf16(afrag0, bfrag0, acc, 0, 0, 0);
        acc = __builtin_amdgcn_mfma_f32_16x16x32_bf16(afrag1, bfrag1, acc, 0, 0, 0);
        // acc[r] = s for (i = i0w + kgrp*4 + r, j = jbase + jt*16 + lrow),
        // already scaled by 1/sqrt(E) via kbf pre-scale.

        const int jl = (jt * 16 + lrow) * 3;
        const float pjx = posS[jl + 0];
        const float pjy = posS[jl + 1];
        const float pjz = posS[jl + 2];

        #pragma unroll
        for (int r = 0; r < 4; ++r) {
            const float dx = pix[r] - pjx;
            const float dy = piy[r] - pjy;
            const float dz = piz[r] - pjz;
            const float r2 = dx * dx + dy * dy + dz * dz;
            const float inv = rsqrtf(r2);
            const float w = (r2 > 1e-12f) ? acc[r] * inv : 0.f;  // diagonal -> 0
            ax[r] += dx * w;
            ay[r] += dy * w;
            az[r] += dz * w;
        }
    }

    // reduce over the 16 j-lanes sharing each i row
    #pragma unroll
    for (int off = 1; off <= 8; off <<= 1) {
        #pragma unroll
        for (int r = 0; r < 4; ++r) {
            ax[r] += __shfl_xor(ax[r], off, 64);
            ay[r] += __shfl_xor(ay[r], off, 64);
            az[r] += __shfl_xor(az[r], off, 64);
        }
    }

    if (lrow == 0) {
        #pragma unroll
        for (int r = 0; r < 4; ++r) {
            const int row = b * NN + i0w + kgrp * 4 + r;
            float* pp = partial + (size_t)jc * (BB * NN * 3) + row * 3;
            pp[0] = ax[r];
            pp[1] = ay[r];
            pp[2] = az[r];
        }
    }
}

// ---------------------------------------------------------------------------
// Kernel C: finalize — sum partials, /msum, tanh, mask. One block per batch.
// ---------------------------------------------------------------------------
__global__ __launch_bounds__(256) void finalize_kernel(
    const float* __restrict__ partial, const float* __restrict__ mask,
    float* __restrict__ out)
{
    __shared__ float wsum[4];
    const int t = threadIdx.x;
    const int b = blockIdx.x;

    float pm = mask[b * NN + t] + mask[b * NN + 256 + t]
             + mask[b * NN + 512 + t] + mask[b * NN + 768 + t];
    #pragma unroll
    for (int off = 32; off; off >>= 1) pm += __shfl_xor(pm, off, 64);
    if ((t & 63) == 0) wsum[t >> 6] = pm;
    __syncthreads();
    const float inv = 1.f / (wsum[0] + wsum[1] + wsum[2] + wsum[3]);

    for (int idx = t; idx < NN * 3; idx += 256) {
        float s = 0.f;
        #pragma unroll
        for (int jc = 0; jc < JC; ++jc)
            s += partial[(size_t)jc * (BB * NN * 3) + b * NN * 3 + idx];
        out[b * NN * 3 + idx] = tanhf(s * inv) * mask[b * NN + idx / 3];
    }
}

// ---------------------------------------------------------------------------
extern "C" void kernel_launch(void* const* d_in, const int* in_sizes, int n_in,
                              void* d_out, int out_size, void* d_ws, size_t ws_size,
                              hipStream_t stream) {
    const float* pos  = (const float*)d_in[0];   // (8,1024,3)
    const float* mask = (const float*)d_in[1];   // (8,1024)
    const float* h    = (const float*)d_in[2];   // (8,1024,128)
    const float* W1   = (const float*)d_in[3];   // (128,64)
    const float* b1   = (const float*)d_in[4];   // (64,)
    const float* W2   = (const float*)d_in[5];   // (64,129)
    const float* b2   = (const float*)d_in[6];   // (129,)
    float* out = (float*)d_out;                  // (8,1024,3)

    __hip_bfloat16* kbf = (__hip_bfloat16*)d_ws;          // 1 MB
    __hip_bfloat16* vbf = kbf + BB * NN * EE;             // 1 MB
    float* partial = (float*)(vbf + BB * NN * EE);        // JC*8192*3 f32 = 768 KB

    mlp_kernel<<<BB * NN / 16, 256, 0, stream>>>(h, W1, b1, W2, b2, mask, kbf, vbf);
    pair_kernel<<<BB * 16 * JC, 256, 0, stream>>>(kbf, vbf, pos, partial);
    finalize_kernel<<<BB, 256, 0, stream>>>(partial, mask, out);
}

// Round 3
// 30.613 us; speedup vs baseline: 2.7505x; 1.2540x over previous
//
#include <hip/hip_runtime.h>
#include <hip/hip_fp16.h>
#include <math.h>

// Problem dims (fixed by the reference)
#define BB 8
#define NN 1024
#define FF 128
#define EE 64
#define JC 8              // j-chunks (parallelism + partial buffers)
#define LOG2F_ 0.69314718055994531f

typedef __attribute__((ext_vector_type(4))) float f32x4;
typedef __attribute__((ext_vector_type(8))) _Float16 f16x8;

__device__ __forceinline__ float softplus_shift(float x) {
    // softplus(x) - log(2), numerically stable
    return fmaxf(x, 0.f) + log1pf(expf(-fabsf(x))) - LOG2F_;
}

// ---------------------------------------------------------------------------
// Kernel A: per-row MLP via MFMA (f16 in, f32 acc).
// One wave per block, 16 rows per wave, 512 blocks.
//   stage1: pre(16x64) = H(16x128) @ W1(128x64) + b1 ; hid = softplus-log2
//   stage2: kv(16x128) = hid(16x64) @ W2(64x128)  + b2 ; mask; k pre-scaled
// hid transposed through 2.3 KB of LDS between stages.
// ---------------------------------------------------------------------------
__global__ __launch_bounds__(64) void mlp_kernel(
    const float* __restrict__ h,  const float* __restrict__ W1,
    const float* __restrict__ b1, const float* __restrict__ W2,
    const float* __restrict__ b2, const float* __restrict__ mask,
    _Float16* __restrict__ kf, _Float16* __restrict__ vf)
{
    __shared__ _Float16 hidS[16][72];   // +8 pad: 16B-aligned rows, bank-spread

    const int lane = threadIdx.x;       // 0..63
    const int lrow = lane & 15;         // A row / B col within 16
    const int kgrp = lane >> 4;
    const int row0 = blockIdx.x * 16;

    // --- A-frags: 16 H rows, 4 k-chunks of 32 ---
    f16x8 hf[4];
    const float* hrow = h + (size_t)(row0 + lrow) * FF;
    #pragma unroll
    for (int kk = 0; kk < 4; ++kk) {
        float t[8];
        *(float4*)&t[0] = *(const float4*)&hrow[kk * 32 + kgrp * 8];
        *(float4*)&t[4] = *(const float4*)&hrow[kk * 32 + kgrp * 8 + 4];
        #pragma unroll
        for (int q = 0; q < 8; ++q) hf[kk][q] = (_Float16)t[q];
    }

    // --- B-frags: W1 columns (scattered f32 loads, W1 is 32 KB / L2-hot) ---
    f16x8 w1f[4][4];
    #pragma unroll
    for (int c = 0; c < 4; ++c)
        #pragma unroll
        for (int kk = 0; kk < 4; ++kk)
            #pragma unroll
            for (int q = 0; q < 8; ++q)
                w1f[c][kk][q] = (_Float16)W1[(kk * 32 + kgrp * 8 + q) * EE + c * 16 + lrow];

    // --- stage 1 MFMA ---
    f32x4 acc1[4];
    #pragma unroll
    for (int c = 0; c < 4; ++c) acc1[c] = (f32x4){0.f, 0.f, 0.f, 0.f};
    #pragma unroll
    for (int c = 0; c < 4; ++c)
        #pragma unroll
        for (int kk = 0; kk < 4; ++kk)
            acc1[c] = __builtin_amdgcn_mfma_f32_16x16x32_f16(hf[kk], w1f[c][kk], acc1[c], 0, 0, 0);

    // --- softplus epilogue -> LDS transpose ---
    #pragma unroll
    for (int c = 0; c < 4; ++c) {
        const float b1c = b1[c * 16 + lrow];
        #pragma unroll
        for (int r = 0; r < 4; ++r)
            hidS[kgrp * 4 + r][c * 16 + lrow] = (_Float16)softplus_shift(acc1[c][r] + b1c);
    }
    __syncthreads();

    // --- stage 2 A-frags from LDS ---
    f16x8 af2[2];
    #pragma unroll
    for (int kk = 0; kk < 2; ++kk)
        af2[kk] = *(const f16x8*)&hidS[lrow][kk * 32 + kgrp * 8];

    // --- stage 2 MFMA (B-frags loaded per col-tile; W2 is 33 KB / L2-hot) ---
    f32x4 acc2[8];
    #pragma unroll
    for (int c2 = 0; c2 < 8; ++c2) acc2[c2] = (f32x4){0.f, 0.f, 0.f, 0.f};
    #pragma unroll
    for (int c2 = 0; c2 < 8; ++c2) {
        #pragma unroll
        for (int kk = 0; kk < 2; ++kk) {
            f16x8 w2f;
            #pragma unroll
            for (int q = 0; q < 8; ++q)
                w2f[q] = (_Float16)W2[(kk * 32 + kgrp * 8 + q) * 129 + c2 * 16 + lrow];
            acc2[c2] = __builtin_amdgcn_mfma_f32_16x16x32_f16(af2[kk], w2f, acc2[c2], 0, 0, 0);
        }
    }

    // --- epilogue: bias, mask, k pre-scale 1/sqrt(E), store f16 ---
    float mrow[4];
    #pragma unroll
    for (int r = 0; r < 4; ++r) mrow[r] = mask[row0 + kgrp * 4 + r];

    #pragma unroll
    for (int c2 = 0; c2 < 8; ++c2) {
        const float b2c = b2[c2 * 16 + lrow];
        #pragma unroll
        for (int r = 0; r < 4; ++r) {
            const int row = row0 + kgrp * 4 + r;
            const float val = (acc2[c2][r] + b2c) * mrow[r];
            if (c2 < 4)
                kf[row * EE + c2 * 16 + lrow] = (_Float16)(val * 0.125f);
            else
                vf[row * EE + (c2 - 4) * 16 + lrow] = (_Float16)val;
        }
    }
}

// ---------------------------------------------------------------------------
// Kernel B: pairwise stage via MFMA (f16).
// Grid = BB * 16 * JC blocks x 256 threads (4 waves).
// Each wave owns a 16-row i-strip (A-frags = k rows, resident in VGPRs) and
// sweeps its block's 128-wide j-chunk in 16-j tiles; B-frags (v rows) come
// straight from L2-resident global. Epilogue: w = s*rsqrt(r2), acc dir*w.
// Partials (per j-chunk) written to ws; no atomics.
// ---------------------------------------------------------------------------
__global__ __launch_bounds__(256) void pair_kernel(
    const _Float16* __restrict__ kf,
    const _Float16* __restrict__ vf,
    const float* __restrict__ pos,
    float* __restrict__ partial)
{
    __shared__ float posS[(NN / JC) * 3];   // this block's j-chunk positions

    const int t = threadIdx.x;
    const int wave = t >> 6;
    const int lane = t & 63;

    const int bx = blockIdx.x;
    const int b  = bx / (16 * JC);
    const int rem = bx % (16 * JC);
    const int ib = rem / JC;               // i-block of 64 rows
    const int jc = rem % JC;               // j-chunk of 128 cols
    const int i0w = ib * 64 + wave * 16;   // wave's 16-row i-strip
    const int jbase = jc * (NN / JC);

    for (int idx = t; idx < (NN / JC) * 3; idx += 256)
        posS[idx] = pos[(b * NN + jbase) * 3 + idx];
    __syncthreads();

    const int lrow = lane & 15;
    const int kgrp = lane >> 4;

    const f16x8 afrag0 = *(const f16x8*)&kf[(b * NN + i0w + lrow) * EE + kgrp * 8];
    const f16x8 afrag1 = *(const f16x8*)&kf[(b * NN + i0w + lrow) * EE + 32 + kgrp * 8];

    float pix[4], piy[4], piz[4];
    #pragma unroll
    for (int r = 0; r < 4; ++r) {
        const int ir = (b * NN + i0w + kgrp * 4 + r) * 3;
        pix[r] = pos[ir + 0];
        piy[r] = pos[ir + 1];
        piz[r] = pos[ir + 2];
    }

    float ax[4] = {0.f, 0.f, 0.f, 0.f};
    float ay[4] = {0.f, 0.f, 0.f, 0.f};
    float az[4] = {0.f, 0.f, 0.f, 0.f};

    for (int jt = 0; jt < (NN / JC) / 16; ++jt) {
        const int jrow = (b * NN + jbase + jt * 16 + lrow) * EE;
        const f16x8 bfrag0 = *(const f16x8*)&vf[jrow + kgrp * 8];
        const f16x8 bfrag1 = *(const f16x8*)&vf[jrow + 32 + kgrp * 8];

        f32x4 acc = {0.f, 0.f, 0.f, 0.f};
        acc = __builtin_amdgcn_mfma_f32_16x16x32_f16(afrag0, bfrag0, acc, 0, 0, 0);
        acc = __builtin_amdgcn_mfma_f32_16x16x32_f16(afrag1, bfrag1, acc, 0, 0, 0);
        // acc[r] = s(i = i0w+kgrp*4+r, j = jbase+jt*16+lrow), pre-scaled 1/8.

        const int jl = (jt * 16 + lrow) * 3;
        const float pjx = posS[jl + 0];
        const float pjy = posS[jl + 1];
        const float pjz = posS[jl + 2];

        #pragma unroll
        for (int r = 0; r < 4; ++r) {
            const float dx = pix[r] - pjx;
            const float dy = piy[r] - pjy;
            const float dz = piz[r] - pjz;
            const float r2 = dx * dx + dy * dy + dz * dz;
            const float inv = rsqrtf(r2);
            const float w = (r2 > 1e-12f) ? acc[r] * inv : 0.f;  // diagonal -> 0
            ax[r] += dx * w;
            ay[r] += dy * w;
            az[r] += dz * w;
        }
    }

    // reduce over the 16 j-lanes sharing each i row
    #pragma unroll
    for (int off = 1; off <= 8; off <<= 1) {
        #pragma unroll
        for (int r = 0; r < 4; ++r) {
            ax[r] += __shfl_xor(ax[r], off, 64);
            ay[r] += __shfl_xor(ay[r], off, 64);
            az[r] += __shfl_xor(az[r], off, 64);
        }
    }

    if (lrow == 0) {
        #pragma unroll
        for (int r = 0; r < 4; ++r) {
            const int row = b * NN + i0w + kgrp * 4 + r;
            float* pp = partial + (size_t)jc * (BB * NN * 3) + row * 3;
            pp[0] = ax[r];
            pp[1] = ay[r];
            pp[2] = az[r];
        }
    }
}

// ---------------------------------------------------------------------------
// Kernel C: finalize — sum partials, /msum, tanh, mask.
// 8 blocks per batch (64 total), each handles 128 rows.
// ---------------------------------------------------------------------------
__global__ __launch_bounds__(256) void finalize_kernel(
    const float* __restrict__ partial, const float* __restrict__ mask,
    float* __restrict__ out)
{
    __shared__ float wsum[4];
    const int t = threadIdx.x;
    const int b = blockIdx.x >> 3;
    const int p = blockIdx.x & 7;

    // batch mask sum (recomputed per block; 1 KB of L2 reads)
    float pm = mask[b * NN + t] + mask[b * NN + 256 + t]
             + mask[b * NN + 512 + t] + mask[b * NN + 768 + t];
    #pragma unroll
    for (int off = 32; off; off >>= 1) pm += __shfl_xor(pm, off, 64);
    if ((t & 63) == 0) wsum[t >> 6] = pm;
    __syncthreads();
    const float inv = 1.f / (wsum[0] + wsum[1] + wsum[2] + wsum[3]);

    const int base = b * NN * 3 + p * 384;      // 128 rows * 3
    for (int idx = t; idx < 384; idx += 256) {
        float s = 0.f;
        #pragma unroll
        for (int jc = 0; jc < JC; ++jc)
            s += partial[(size_t)jc * (BB * NN * 3) + base + idx];
        const float m = mask[b * NN + p * 128 + idx / 3];
        out[base + idx] = tanhf(s * inv) * m;
    }
}

// ---------------------------------------------------------------------------
extern "C" void kernel_launch(void* const* d_in, const int* in_sizes, int n_in,
                              void* d_out, int out_size, void* d_ws, size_t ws_size,
                              hipStream_t stream) {
    const float* pos  = (const float*)d_in[0];   // (8,1024,3)
    const float* mask = (const float*)d_in[1];   // (8,1024)
    const float* h    = (const float*)d_in[2];   // (8,1024,128)
    const float* W1   = (const float*)d_in[3];   // (128,64)
    const float* b1   = (const float*)d_in[4];   // (64,)
    const float* W2   = (const float*)d_in[5];   // (64,129)
    const float* b2   = (const float*)d_in[6];   // (129,)
    float* out = (float*)d_out;                  // (8,1024,3)

    _Float16* kf = (_Float16*)d_ws;              // 1 MB
    _Float16* vf = kf + BB * NN * EE;            // 1 MB
    float* partial = (float*)(vf + BB * NN * EE);// JC*8192*3 f32 = 768 KB

    mlp_kernel<<<BB * NN / 16, 64, 0, stream>>>(h, W1, b1, W2, b2, mask, kf, vf);
    pair_kernel<<<BB * 16 * JC, 256, 0, stream>>>(kf, vf, pos, partial);
    finalize_kernel<<<BB * 8, 256, 0, stream>>>(partial, mask, out);
}